// Round 9
// baseline (169.549 us; speedup 1.0000x reference)
//
#include <hip/hip_runtime.h>
#include <hip/hip_bf16.h>

#define B_TOTAL 4096
#define LOG2E 1.44269504088896f

typedef short short8 __attribute__((ext_vector_type(8)));
typedef float f32x4 __attribute__((ext_vector_type(4)));
typedef float f32x2 __attribute__((ext_vector_type(2)));
typedef int   i32x4 __attribute__((ext_vector_type(4)));

__device__ __forceinline__ unsigned short rne_bf16(float x) {
    unsigned int u = __float_as_uint(x);
    unsigned int r = (u + 0x7fffu + ((u >> 16) & 1u)) >> 16;
    return (unsigned short)r;
}
__device__ __forceinline__ unsigned int cvt2bf(float lo, float hi) {
    unsigned int r;
    asm("v_cvt_pk_bf16_f32 %0, %1, %2" : "=v"(r) : "v"(lo), "v"(hi));
    return r;
}
__device__ __forceinline__ f32x2 v2(float x) { f32x2 r; r[0] = x; r[1] = x; return r; }

// ---------------- Kernel A: neighbor mean ----------------
__global__ __launch_bounds__(256) void k_neighbor_mean(
    const float* __restrict__ matrix,   // [B,64,64]
    const float* __restrict__ features, // [B,64,6]
    float* __restrict__ upd)            // [B,64,6]
{
    __shared__ float adj[64][65];
    __shared__ float fx[64][6];
    const int b = blockIdx.x;
    const int tid = threadIdx.x;
    const float* mb_ = matrix + (size_t)b * 4096;
    for (int idx = tid; idx < 4096; idx += 256) adj[idx >> 6][idx & 63] = mb_[idx];
    const float* fb = features + (size_t)b * 384;
    for (int idx = tid; idx < 384; idx += 256) fx[idx / 6][idx % 6] = fb[idx];
    __syncthreads();
    if (tid < 64) {
        const int i = tid;
        float s0=0,s1=0,s2=0,s3=0,s4=0,s5=0,cnt=0;
        for (int j = 0; j < 64; j++) {
            float m = adj[i][j] > 0.0f ? 1.0f : 0.0f;
            cnt += m;
            s0 += m*fx[j][0]; s1 += m*fx[j][1]; s2 += m*fx[j][2];
            s3 += m*fx[j][3]; s4 += m*fx[j][4]; s5 += m*fx[j][5];
        }
        const float inv = 1.0f / (cnt + 1.0f);
        float* o = upd + (size_t)b * 384 + i * 6;
        o[0]=(s0+fx[i][0])*inv; o[1]=(s1+fx[i][1])*inv; o[2]=(s2+fx[i][2])*inv;
        o[3]=(s3+fx[i][3])*inv; o[4]=(s4+fx[i][4])*inv; o[5]=(s5+fx[i][5])*inv;
    }
}

// ---------------- Kernel W: weights -> i8 digit A-fragments (log2e-folded) ----------------
// Wd1/Wd2 [dir 2][mtg 32][kc 2][lane 64][e 16] i8:
//   n = mtg*16 + (lane&15), j = (n&3)*128 + (n>>2)   (n = 4*hu + gate)
//   ks = kc*64 + 16*(lane>>4) + e; hu_src = 8*(ks>>3) + 4*(ks&1) + ((ks&7)>>1)
//   a = Wh[j*128+hu_src] * 512*LOG2E (== 256*2*LOG2E, gate-uniform);
//   d1 = rint(a), d2 = rint((a-d1)*128)
// AwU [dir 2][mtg 32][lane 64][e 8] bf16 : Wi * (gate==2 ? 2L : L); nonzero only lane>>4==0 && e<6
// Bq  [dir 2][n 512] f32 : (bi+bh) * (gate==2 ? 2L : L)
__global__ __launch_bounds__(256) void k_wprep5(
    const float* __restrict__ Wi_f, const float* __restrict__ Wh_f,
    const float* __restrict__ bi_f, const float* __restrict__ bh_f,
    const float* __restrict__ Wi_b, const float* __restrict__ Wh_b,
    const float* __restrict__ bi_b, const float* __restrict__ bh_b,
    signed char* __restrict__ Wd1, signed char* __restrict__ Wd2,
    unsigned short* __restrict__ AwU, float* __restrict__ BqO)
{
    const int idx = blockIdx.x * 256 + threadIdx.x;   // 0..164863
    if (idx < 131072) {
        const int dir = idx >> 16;
        const int r = idx & 65535;
        const int mtg = r >> 11;
        const int kc  = (r >> 10) & 1;
        const int l   = (r >> 4) & 63;
        const int e   = r & 15;
        const int n = mtg * 16 + (l & 15);
        const int j = ((n & 3) << 7) + (n >> 2);
        const int ks = kc * 64 + 16 * (l >> 4) + e;   // 0..127
        const int hu = 8 * (ks >> 3) + 4 * (ks & 1) + ((ks & 7) >> 1);
        const float w = (dir ? Wh_b : Wh_f)[j * 128 + hu];
        const float a = w * (512.0f * LOG2E);
        const float r1 = rintf(a);
        Wd1[idx] = (signed char)(int)r1;
        Wd2[idx] = (signed char)(int)rintf((a - r1) * 128.0f);
    } else if (idx < 163840) {
        const int i2 = idx - 131072;       // 0..32767
        const int dir = i2 >> 14;
        const int r = i2 & 16383;
        const int mtg = r >> 9, l = (r >> 3) & 63, e = r & 7;
        const int n = mtg * 16 + (l & 15);
        const int j = ((n & 3) << 7) + (n >> 2);
        const float sc = ((n & 3) == 2) ? 2.0f * LOG2E : LOG2E;
        float w = 0.0f;
        if ((l >> 4) == 0 && e < 6) w = (dir ? Wi_b : Wi_f)[j * 6 + e] * sc;
        AwU[i2] = rne_bf16(w);
    } else if (idx < 164864) {
        const int i2 = idx - 163840;       // 0..1023
        const int dir = i2 >> 9;
        const int n = i2 & 511;
        const int j = ((n & 3) << 7) + (n >> 2);
        const float sc = ((n & 3) == 2) ? 2.0f * LOG2E : LOG2E;
        BqO[i2] = ((dir ? bi_b : bi_f)[j] + (dir ? bh_b : bh_f)[j]) * sc;
    }
}

// ---------------- Kernel B: i8 MFMA bi-LSTM, 16 batches/block, 2 blocks/CU ----------------
// grid (256, 2), block 1024 (16 waves). Wave owns mtg {2w,2w+1} (hu 8w..8w+7) x 16 batches.
// Per step (R6-proven structure): read h -> 14 MFMAs -> cell math (native f32x2 over the
// mt pair) -> digit writes -> ONE barrier. Cross-block drift provides MFMA/VALU overlap.
__global__ __launch_bounds__(1024) void k_lstm10(
    const float* __restrict__ upd,          // [4096][64][6]
    const signed char* __restrict__ Wd1,    // [2][32][2][64][16]
    const signed char* __restrict__ Wd2,    // [2][32][2][64][16]
    const unsigned short* __restrict__ AwU, // [2][32][64][8]
    const float* __restrict__ Bq,           // [2][512]
    float* __restrict__ hout)               // [2][4096][128]
{
    // H: byte = digit*8192 + buf*4096 + row(l15)*144 + col(p(hu))   (16 KB)
    __shared__ i32x4 HsV[1024];
    // U: byte = t*256 + b*16  (bf16x8 {u0..u5,0,0})                 (16 KB)
    __shared__ i32x4 UsV[1024];
    char* Hb = (char*)HsV;
    char* Ub = (char*)UsV;
    const int tid  = threadIdx.x;
    const int wave = tid >> 6;
    const int lane = tid & 63;
    const int dir  = blockIdx.y;
    const int b0   = blockIdx.x * 16;
    const int l15  = lane & 15;
    const int lhi  = lane >> 4;
    const int hu0  = 8 * wave + lhi, hu1 = hu0 + 4;

    // persistent: wd 32 + awu 8 + bias 8 + cs 2
    i32x4 wd1[2][2], wd2[2][2];
    short8 awu[2];
    f32x4 bias[2];
    #pragma unroll
    for (int mt = 0; mt < 2; mt++) {
        const int mtg = 2 * wave + mt;
        #pragma unroll
        for (int kc = 0; kc < 2; kc++) {
            wd1[mt][kc] = *(const i32x4*)(Wd1 + dir * 65536 + mtg * 2048 + kc * 1024 + lane * 16);
            wd2[mt][kc] = *(const i32x4*)(Wd2 + dir * 65536 + mtg * 2048 + kc * 1024 + lane * 16);
        }
        awu[mt]  = *(const short8*)(AwU + dir * 16384 + mtg * 512 + lane * 8);
        bias[mt] = *(const f32x4*)(Bq + dir * 512 + mtg * 16 + 4 * lhi);
    }

    // stage u hi-fragments: 64 steps x 16 batches (exactly 1024 frags)
    {
        const int t = tid >> 4, b = tid & 15;
        const float2* p = (const float2*)(upd + (size_t)(b0 + b) * 384 + t * 6);
        const float2 a0 = p[0], a1 = p[1], a2 = p[2];
        i32x4 v;
        v[0] = (int)cvt2bf(a0.x, a0.y);
        v[1] = (int)cvt2bf(a1.x, a1.y);
        v[2] = (int)cvt2bf(a2.x, a2.y);
        v[3] = 0;
        *(i32x4*)(Ub + t * 256 + b * 16) = v;
    }
    // zero all h digit planes (16 KB, one int4 per thread)
    {
        i32x4 z4; z4[0] = 0; z4[1] = 0; z4[2] = 0; z4[3] = 0;
        *(i32x4*)(Hb + tid * 16) = z4;
    }

    int ra = 4096 + l15 * 144 + lhi * 16;                // read buf1 at s=0
    int wa = l15 * 144 + 8 * wave + 2 * lhi;             // write buf0 at s=0
    f32x2 cs = v2(0.0f);
    __syncthreads();

    const i32x4 zi = {0, 0, 0, 0};
    const f32x2 one2 = v2(1.0f);
    const f32x2 two2 = v2(2.0f);

    #pragma unroll 1
    for (int s = 0; s < 64; ++s) {
        const int t = dir ? (63 - s) : s;
        const short8 fu = *(const short8*)(Ub + t * 256 + l15 * 16);

        // ---- read h digits, issue all 14 MFMAs ----
        const i32x4 h1k0 = *(const i32x4*)(Hb + ra);
        const i32x4 h1k1 = *(const i32x4*)(Hb + ra + 64);
        const i32x4 h2k0 = *(const i32x4*)(Hb + ra + 8192);
        const i32x4 h2k1 = *(const i32x4*)(Hb + ra + 8256);
        f32x4 Ua[2];
        i32x4 Aa[2], Ba[2];
        __builtin_amdgcn_s_setprio(1);
        #pragma unroll
        for (int mt = 0; mt < 2; mt++) {
            Ua[mt] = __builtin_amdgcn_mfma_f32_16x16x32_bf16(awu[mt], fu, bias[mt], 0, 0, 0);
            i32x4 a = __builtin_amdgcn_mfma_i32_16x16x64_i8(wd1[mt][0], h1k0, zi, 0, 0, 0);
            a = __builtin_amdgcn_mfma_i32_16x16x64_i8(wd1[mt][1], h1k1, a, 0, 0, 0);
            i32x4 b = __builtin_amdgcn_mfma_i32_16x16x64_i8(wd1[mt][0], h2k0, zi, 0, 0, 0);
            b = __builtin_amdgcn_mfma_i32_16x16x64_i8(wd1[mt][1], h2k1, b, 0, 0, 0);
            b = __builtin_amdgcn_mfma_i32_16x16x64_i8(wd2[mt][0], h1k0, b, 0, 0, 0);
            b = __builtin_amdgcn_mfma_i32_16x16x64_i8(wd2[mt][1], h1k1, b, 0, 0, 0);
            Aa[mt] = a; Ba[mt] = b;
        }
        __builtin_amdgcn_s_setprio(0);
        ra ^= 0x1000;

        // ---- cell math, native f32x2 over the mt pair (R7 formulas, no inline asm) ----
        f32x2 zv[4];
        #pragma unroll
        for (int i = 0; i < 4; i++) {
            const int T0 = (Aa[0][i] << 7) + Ba[0][i];
            const int T1 = (Aa[1][i] << 7) + Ba[1][i];
            const float sc = (i == 2) ? 0x1p-21f : 0x1p-22f;
            f32x2 zf;
            zf[0] = fmaf((float)T0, sc, Ua[0][i]);
            zf[1] = fmaf((float)T1, sc, Ua[1][i]);
            zv[i] = zf;
        }
        f32x2 E0, E1, E2, E3;
        E0[0] = __builtin_amdgcn_exp2f(-zv[0][0]); E0[1] = __builtin_amdgcn_exp2f(-zv[0][1]);
        E1[0] = __builtin_amdgcn_exp2f(-zv[1][0]); E1[1] = __builtin_amdgcn_exp2f(-zv[1][1]);
        E2[0] = __builtin_amdgcn_exp2f( zv[2][0]); E2[1] = __builtin_amdgcn_exp2f( zv[2][1]);
        E3[0] = __builtin_amdgcn_exp2f(-zv[3][0]); E3[1] = __builtin_amdgcn_exp2f(-zv[3][1]);
        const f32x2 D0 = E0 + one2;
        const f32x2 D1 = E1 + one2;
        const f32x2 D2 = E2 + one2;
        const f32x2 D3 = E3 + one2;
        const f32x2 P2 = D0 * D1, P3 = P2 * D2, P4 = P3 * D3;
        f32x2 rr;
        rr[0] = __builtin_amdgcn_rcpf(P4[0]);
        rr[1] = __builtin_amdgcn_rcpf(P4[1]);
        const f32x2 Q2 = D3 * D2, Q3 = Q2 * D1;
        const f32x2 ig = rr * Q3;
        const f32x2 fg = rr * Q2 * D0;
        const f32x2 og = rr * P3;
        const f32x2 gg = one2 - two2 * (rr * P2 * D3);
        cs = fg * cs + ig * gg;
        // tanh(c): grouped reciprocal across the mt pair
        const float aa0 = fminf(cs[0] * (2.0f * LOG2E), 30.0f);
        const float aa1 = fminf(cs[1] * (2.0f * LOG2E), 30.0f);
        const float Dq0 = 1.0f + __builtin_amdgcn_exp2f(aa0);
        const float Dq1 = 1.0f + __builtin_amdgcn_exp2f(aa1);
        const float rq = __builtin_amdgcn_rcpf(Dq0 * Dq1);
        const float hh0 = og[0] * fmaf(-2.0f, rq * Dq1, 1.0f);
        const float hh1 = og[1] * fmaf(-2.0f, rq * Dq0, 1.0f);

        if (s < 63) {
            // digit encode via magic number, packed 2-byte writes
            const int t0 = __float_as_int(fmaf(hh0, 8192.0f, 12582912.0f)) - 0x4B400000;
            const int t1 = __float_as_int(fmaf(hh1, 8192.0f, 12582912.0f)) - 0x4B400000;
            const int d10 = (t0 + 64) >> 7;
            const int d20 = t0 - (d10 << 7);
            const int d11 = (t1 + 64) >> 7;
            const int d21 = t1 - (d11 << 7);
            *(unsigned short*)(Hb + wa) =
                (unsigned short)__builtin_amdgcn_perm((unsigned)d11, (unsigned)d10, 0x0400);
            *(unsigned short*)(Hb + wa + 8192) =
                (unsigned short)__builtin_amdgcn_perm((unsigned)d21, (unsigned)d20, 0x0400);
        } else {
            float* o = hout + ((size_t)dir * B_TOTAL + b0 + l15) * 128;
            o[hu0] = hh0;
            o[hu1] = hh1;
        }
        wa ^= 0x1000;
        __syncthreads();
    }
}

// ---------------- Kernel C: final FC ----------------
__global__ __launch_bounds__(256) void k_final(
    const float* __restrict__ hout,        // [2][B][128]
    const float* __restrict__ device_idx,  // [B]
    const float* __restrict__ fc_w,        // [257]
    const float* __restrict__ fc_b,        // [1]
    float* __restrict__ y)                 // [B]
{
    const int wave = threadIdx.x >> 6;
    const int lane = threadIdx.x & 63;
    const int b = blockIdx.x * 4 + wave;
    const float* hf = hout + (size_t)b * 128;
    const float* hb = hout + ((size_t)B_TOTAL + b) * 128;
    float p = fc_w[1 + lane]        * hf[lane]
            + fc_w[1 + 64 + lane]   * hf[64 + lane]
            + fc_w[129 + lane]      * hb[lane]
            + fc_w[129 + 64 + lane] * hb[64 + lane];
    #pragma unroll
    for (int off = 32; off; off >>= 1) p += __shfl_xor(p, off, 64);
    if (lane == 0) y[b] = p + fc_w[0] * device_idx[b] + fc_b[0];
}

extern "C" void kernel_launch(void* const* d_in, const int* in_sizes, int n_in,
                              void* d_out, int out_size, void* d_ws, size_t ws_size,
                              hipStream_t stream) {
    const float* device_idx = (const float*)d_in[0];
    const float* matrix     = (const float*)d_in[1];
    const float* features   = (const float*)d_in[2];
    const float* Wi_f = (const float*)d_in[3];
    const float* Wh_f = (const float*)d_in[4];
    const float* bi_f = (const float*)d_in[5];
    const float* bh_f = (const float*)d_in[6];
    const float* Wi_b = (const float*)d_in[7];
    const float* Wh_b = (const float*)d_in[8];
    const float* bi_b = (const float*)d_in[9];
    const float* bh_b = (const float*)d_in[10];
    const float* fc_w = (const float*)d_in[11];
    const float* fc_b = (const float*)d_in[12];
    float* out = (float*)d_out;

    float* ws = (float*)d_ws;
    float*          upd  = ws;                               // 1,572,864 floats
    signed char*    Wd1  = (signed char*)(ws + 1572864);     // 131,072 bytes
    signed char*    Wd2  = (signed char*)(ws + 1605632);     // 131,072 bytes
    unsigned short* AwU  = (unsigned short*)(ws + 1638400);  //  32,768 ushorts
    float*          Bq   = ws + 1654784;                     //   1,024 floats
    float*          hout = ws + 1655808;                     // 1,048,576 floats

    hipLaunchKernelGGL(k_neighbor_mean, dim3(B_TOTAL), dim3(256), 0, stream,
                       matrix, features, upd);
    hipLaunchKernelGGL(k_wprep5, dim3(644), dim3(256), 0, stream,
                       Wi_f, Wh_f, bi_f, bh_f, Wi_b, Wh_b, bi_b, bh_b,
                       Wd1, Wd2, AwU, Bq);
    hipLaunchKernelGGL(k_lstm10, dim3(B_TOTAL / 16, 2), dim3(1024), 0, stream,
                       upd, Wd1, Wd2, AwU, Bq, hout);
    hipLaunchKernelGGL(k_final, dim3(B_TOTAL / 4), dim3(256), 0, stream,
                       hout, device_idx, fc_w, fc_b, out);
}

// Round 10
// 168.398 us; speedup vs baseline: 1.0068x; 1.0068x over previous
//
#include <hip/hip_runtime.h>
#include <hip/hip_bf16.h>

#define B_TOTAL 4096
#define LOG2E 1.44269504088896f

typedef short short8 __attribute__((ext_vector_type(8)));
typedef float f32x4 __attribute__((ext_vector_type(4)));
typedef float f32x2 __attribute__((ext_vector_type(2)));
typedef int   i32x4 __attribute__((ext_vector_type(4)));

__device__ __forceinline__ unsigned short rne_bf16(float x) {
    unsigned int u = __float_as_uint(x);
    unsigned int r = (u + 0x7fffu + ((u >> 16) & 1u)) >> 16;
    return (unsigned short)r;
}
__device__ __forceinline__ unsigned int cvt2bf(float lo, float hi) {
    unsigned int r;
    asm("v_cvt_pk_bf16_f32 %0, %1, %2" : "=v"(r) : "v"(lo), "v"(hi));
    return r;
}
__device__ __forceinline__ f32x2 v2(float x) { f32x2 r; r[0] = x; r[1] = x; return r; }

// ---------------- Kernel A: neighbor mean ----------------
__global__ __launch_bounds__(256) void k_neighbor_mean(
    const float* __restrict__ matrix,   // [B,64,64]
    const float* __restrict__ features, // [B,64,6]
    float* __restrict__ upd)            // [B,64,6]
{
    __shared__ float adj[64][65];
    __shared__ float fx[64][6];
    const int b = blockIdx.x;
    const int tid = threadIdx.x;
    const float* mb_ = matrix + (size_t)b * 4096;
    for (int idx = tid; idx < 4096; idx += 256) adj[idx >> 6][idx & 63] = mb_[idx];
    const float* fb = features + (size_t)b * 384;
    for (int idx = tid; idx < 384; idx += 256) fx[idx / 6][idx % 6] = fb[idx];
    __syncthreads();
    if (tid < 64) {
        const int i = tid;
        float s0=0,s1=0,s2=0,s3=0,s4=0,s5=0,cnt=0;
        for (int j = 0; j < 64; j++) {
            float m = adj[i][j] > 0.0f ? 1.0f : 0.0f;
            cnt += m;
            s0 += m*fx[j][0]; s1 += m*fx[j][1]; s2 += m*fx[j][2];
            s3 += m*fx[j][3]; s4 += m*fx[j][4]; s5 += m*fx[j][5];
        }
        const float inv = 1.0f / (cnt + 1.0f);
        float* o = upd + (size_t)b * 384 + i * 6;
        o[0]=(s0+fx[i][0])*inv; o[1]=(s1+fx[i][1])*inv; o[2]=(s2+fx[i][2])*inv;
        o[3]=(s3+fx[i][3])*inv; o[4]=(s4+fx[i][4])*inv; o[5]=(s5+fx[i][5])*inv;
    }
}

// ---------------- Kernel W: weights -> i8 digit A-fragments (log2e-folded) ----------------
// Wd1/Wd2 [dir 2][mtg 32][kc 2][lane 64][e 16] i8:
//   n = mtg*16 + (lane&15), j = (n&3)*128 + (n>>2)   (n = 4*hu + gate)
//   ks = kc*64 + 16*(lane>>4) + e; hu_src = 8*(ks>>3) + 4*(ks&1) + ((ks&7)>>1)
//   a = Wh[j*128+hu_src] * 512*LOG2E (== 256*2*LOG2E, gate-uniform);
//   d1 = rint(a), d2 = rint((a-d1)*128)
// AwU [dir 2][mtg 32][lane 64][e 8] bf16 : Wi * (gate==2 ? 2L : L); nonzero only lane>>4==0 && e<6
// Bq  [dir 2][n 512] f32 : (bi+bh) * (gate==2 ? 2L : L)
__global__ __launch_bounds__(256) void k_wprep5(
    const float* __restrict__ Wi_f, const float* __restrict__ Wh_f,
    const float* __restrict__ bi_f, const float* __restrict__ bh_f,
    const float* __restrict__ Wi_b, const float* __restrict__ Wh_b,
    const float* __restrict__ bi_b, const float* __restrict__ bh_b,
    signed char* __restrict__ Wd1, signed char* __restrict__ Wd2,
    unsigned short* __restrict__ AwU, float* __restrict__ BqO)
{
    const int idx = blockIdx.x * 256 + threadIdx.x;   // 0..164863
    if (idx < 131072) {
        const int dir = idx >> 16;
        const int r = idx & 65535;
        const int mtg = r >> 11;
        const int kc  = (r >> 10) & 1;
        const int l   = (r >> 4) & 63;
        const int e   = r & 15;
        const int n = mtg * 16 + (l & 15);
        const int j = ((n & 3) << 7) + (n >> 2);
        const int ks = kc * 64 + 16 * (l >> 4) + e;   // 0..127
        const int hu = 8 * (ks >> 3) + 4 * (ks & 1) + ((ks & 7) >> 1);
        const float w = (dir ? Wh_b : Wh_f)[j * 128 + hu];
        const float a = w * (512.0f * LOG2E);
        const float r1 = rintf(a);
        Wd1[idx] = (signed char)(int)r1;
        Wd2[idx] = (signed char)(int)rintf((a - r1) * 128.0f);
    } else if (idx < 163840) {
        const int i2 = idx - 131072;       // 0..32767
        const int dir = i2 >> 14;
        const int r = i2 & 16383;
        const int mtg = r >> 9, l = (r >> 3) & 63, e = r & 7;
        const int n = mtg * 16 + (l & 15);
        const int j = ((n & 3) << 7) + (n >> 2);
        const float sc = ((n & 3) == 2) ? 2.0f * LOG2E : LOG2E;
        float w = 0.0f;
        if ((l >> 4) == 0 && e < 6) w = (dir ? Wi_b : Wi_f)[j * 6 + e] * sc;
        AwU[i2] = rne_bf16(w);
    } else if (idx < 164864) {
        const int i2 = idx - 163840;       // 0..1023
        const int dir = i2 >> 9;
        const int n = i2 & 511;
        const int j = ((n & 3) << 7) + (n >> 2);
        const float sc = ((n & 3) == 2) ? 2.0f * LOG2E : LOG2E;
        BqO[i2] = ((dir ? bi_b : bi_f)[j] + (dir ? bh_b : bh_f)[j]) * sc;
    }
}

// ---------------- Kernel B: group-pipelined i8 MFMA bi-LSTM, pk-f32 cell math ----------------
// grid (128, 2), block 1024 (16 waves), 1 block/CU.
// Wave owns mtg {2w,2w+1} (hu 8w..8w+7) x 32 batches (groups g0=b0..b0+15, g1=+16).
// Interval iv: [z for gc=iv&1 from accs issued last interval] ->
//              [issue 14 MFMAs for gi=gc^1, step (iv+1)>>1] ->
//              [gate/cell/encode for gc, cross-mt f32x2 packed] -> barrier.
__global__ __launch_bounds__(1024) void k_lstm11(
    const float* __restrict__ upd,          // [4096][64][6]
    const signed char* __restrict__ Wd1,    // [2][32][2][64][16]
    const signed char* __restrict__ Wd2,    // [2][32][2][64][16]
    const unsigned short* __restrict__ AwU, // [2][32][64][8]
    const float* __restrict__ Bq,           // [2][512]
    float* __restrict__ hout)               // [2][4096][128]
{
    // H: byte = g*16384 + digit*8192 + buf*4096 + row(l15)*144 + col(p(hu))
    __shared__ i32x4 HsV[2048];   // 32 KB
    // U: byte = g*16384 + t*256 + b*16  (bf16x8 {u0..u5,0,0})
    __shared__ i32x4 UsV[2048];   // 32 KB
    char* Hb = (char*)HsV;
    char* Ub = (char*)UsV;
    const int tid  = threadIdx.x;
    const int wave = tid >> 6;
    const int lane = tid & 63;
    const int dir  = blockIdx.y;
    const int b0   = blockIdx.x * 32;
    const int l15  = lane & 15;
    const int lhi  = lane >> 4;
    const int hu0  = 8 * wave + lhi, hu1 = hu0 + 4;

    // persistent: wd 32 + awu 8 + bias 8 + cs 4
    i32x4 wd1[2][2], wd2[2][2];
    short8 awu[2];
    f32x4 bias[2];
    #pragma unroll
    for (int mt = 0; mt < 2; mt++) {
        const int mtg = 2 * wave + mt;
        #pragma unroll
        for (int kc = 0; kc < 2; kc++) {
            wd1[mt][kc] = *(const i32x4*)(Wd1 + dir * 65536 + mtg * 2048 + kc * 1024 + lane * 16);
            wd2[mt][kc] = *(const i32x4*)(Wd2 + dir * 65536 + mtg * 2048 + kc * 1024 + lane * 16);
        }
        awu[mt]  = *(const short8*)(AwU + dir * 16384 + mtg * 512 + lane * 8);
        bias[mt] = *(const f32x4*)(Bq + dir * 512 + mtg * 16 + 4 * lhi);
    }

    // stage u hi-fragments: 64 steps x 32 batches
    for (int i = tid; i < 2048; i += 1024) {
        const int t = i >> 5, b = i & 31;
        const float2* p = (const float2*)(upd + (size_t)(b0 + b) * 384 + t * 6);
        const float2 a0 = p[0], a1 = p[1], a2 = p[2];
        i32x4 v;
        v[0] = (int)cvt2bf(a0.x, a0.y);
        v[1] = (int)cvt2bf(a1.x, a1.y);
        v[2] = (int)cvt2bf(a2.x, a2.y);
        v[3] = 0;
        *(i32x4*)(Ub + (b >> 4) * 16384 + t * 256 + (b & 15) * 16) = v;
    }
    // zero all h digit planes
    for (int i = tid; i < 8192; i += 1024) ((int*)Hb)[i] = 0;

    int ra[2], wa[2];
    #pragma unroll
    for (int g = 0; g < 2; g++) {
        ra[g] = g * 16384 + 4096 + l15 * 144 + lhi * 16;        // read buf1 first
        wa[g] = g * 16384 + l15 * 144 + 8 * wave + 2 * lhi;     // write buf0 first
    }
    f32x2 cs0 = v2(0.0f), cs1 = v2(0.0f);
    f32x4 Ua[2][2];
    i32x4 Aa[2][2], Ba[2][2];
    __syncthreads();

    const i32x4 zi = {0, 0, 0, 0};
    const f32x2 one2 = v2(1.0f);
    const f32x2 two2 = v2(2.0f);

    // prologue: issue group 0, step 0 (h = zeros)
    {
        const int tt = dir ? 63 : 0;
        const short8 fu = *(const short8*)(Ub + tt * 256 + l15 * 16);
        const i32x4 h1k0 = *(const i32x4*)(Hb + ra[0]);
        const i32x4 h1k1 = *(const i32x4*)(Hb + ra[0] + 64);
        const i32x4 h2k0 = *(const i32x4*)(Hb + ra[0] + 8192);
        const i32x4 h2k1 = *(const i32x4*)(Hb + ra[0] + 8256);
        ra[0] ^= 0x1000;
        #pragma unroll
        for (int mt = 0; mt < 2; mt++) {
            Ua[0][mt] = __builtin_amdgcn_mfma_f32_16x16x32_bf16(awu[mt], fu, bias[mt], 0, 0, 0);
            i32x4 a = __builtin_amdgcn_mfma_i32_16x16x64_i8(wd1[mt][0], h1k0, zi, 0, 0, 0);
            a = __builtin_amdgcn_mfma_i32_16x16x64_i8(wd1[mt][1], h1k1, a, 0, 0, 0);
            i32x4 b = __builtin_amdgcn_mfma_i32_16x16x64_i8(wd1[mt][0], h2k0, zi, 0, 0, 0);
            b = __builtin_amdgcn_mfma_i32_16x16x64_i8(wd1[mt][1], h2k1, b, 0, 0, 0);
            b = __builtin_amdgcn_mfma_i32_16x16x64_i8(wd2[mt][0], h1k0, b, 0, 0, 0);
            b = __builtin_amdgcn_mfma_i32_16x16x64_i8(wd2[mt][1], h1k1, b, 0, 0, 0);
            Aa[0][mt] = a; Ba[0][mt] = b;
        }
    }

    #pragma unroll 2
    for (int iv = 0; iv < 128; ++iv) {
        const int gc = iv & 1;          // group whose cells complete this interval
        const int sc = iv >> 1;
        f32x2& cs = gc ? cs1 : cs0;

        // ---- z assembly for gc: exp2 args with negations folded into fma consts ----
        // gates 0,1,3: arg = -(T*s + U); gate 2: arg = +(T*s2 + U)
        f32x2 ex[4];
        #pragma unroll
        for (int g = 0; g < 4; g++) {
            const int T0 = (Aa[gc][0][g] << 7) + Ba[gc][0][g];
            const int T1 = (Aa[gc][1][g] << 7) + Ba[gc][1][g];
            float a0, a1;
            if (g == 2) {
                a0 = fmaf((float)T0,  0x1p-21f,  Ua[gc][0][g]);
                a1 = fmaf((float)T1,  0x1p-21f,  Ua[gc][1][g]);
            } else {
                a0 = fmaf((float)T0, -0x1p-22f, -Ua[gc][0][g]);
                a1 = fmaf((float)T1, -0x1p-22f, -Ua[gc][1][g]);
            }
            f32x2 e;
            e[0] = __builtin_amdgcn_exp2f(a0);
            e[1] = __builtin_amdgcn_exp2f(a1);
            ex[g] = e;
        }

        // ---- issue next group's MFMAs (overlaps the cell math below) ----
        if (iv < 127) {
            const int gi = gc ^ 1;
            const int si = (iv + 1) >> 1;
            const int tt = dir ? (63 - si) : si;
            const short8 fu = *(const short8*)(Ub + gi * 16384 + tt * 256 + l15 * 16);
            const i32x4 h1k0 = *(const i32x4*)(Hb + ra[gi]);
            const i32x4 h1k1 = *(const i32x4*)(Hb + ra[gi] + 64);
            const i32x4 h2k0 = *(const i32x4*)(Hb + ra[gi] + 8192);
            const i32x4 h2k1 = *(const i32x4*)(Hb + ra[gi] + 8256);
            ra[gi] ^= 0x1000;
            __builtin_amdgcn_s_setprio(1);
            #pragma unroll
            for (int mt = 0; mt < 2; mt++) {
                Ua[gi][mt] = __builtin_amdgcn_mfma_f32_16x16x32_bf16(awu[mt], fu, bias[mt], 0, 0, 0);
                i32x4 a = __builtin_amdgcn_mfma_i32_16x16x64_i8(wd1[mt][0], h1k0, zi, 0, 0, 0);
                a = __builtin_amdgcn_mfma_i32_16x16x64_i8(wd1[mt][1], h1k1, a, 0, 0, 0);
                i32x4 b = __builtin_amdgcn_mfma_i32_16x16x64_i8(wd1[mt][0], h2k0, zi, 0, 0, 0);
                b = __builtin_amdgcn_mfma_i32_16x16x64_i8(wd1[mt][1], h2k1, b, 0, 0, 0);
                b = __builtin_amdgcn_mfma_i32_16x16x64_i8(wd2[mt][0], h1k0, b, 0, 0, 0);
                b = __builtin_amdgcn_mfma_i32_16x16x64_i8(wd2[mt][1], h1k1, b, 0, 0, 0);
                Aa[gi][mt] = a; Ba[gi][mt] = b;
            }
            __builtin_amdgcn_s_setprio(0);
        }

        // ---- gates: cross-mt f32x2 (lowers to v_pk_*_f32), one rcp for all 8 denoms ----
        const f32x2 D0 = ex[0] + one2;
        const f32x2 D1 = ex[1] + one2;
        const f32x2 D2 = ex[2] + one2;
        const f32x2 D3 = ex[3] + one2;
        const f32x2 P2 = D0 * D1, P3 = P2 * D2, P4 = P3 * D3;
        const float rall = __builtin_amdgcn_rcpf(P4[0] * P4[1]);
        f32x2 rv;
        rv[0] = rall * P4[1];
        rv[1] = rall * P4[0];
        const f32x2 Q2 = D3 * D2, Q3 = Q2 * D1;
        const f32x2 ig = rv * Q3;
        const f32x2 fg = rv * Q2 * D0;
        const f32x2 og = rv * P3;
        const f32x2 gg = one2 - two2 * (rv * P2 * D3);
        cs = fg * cs + ig * gg;
        // tanh(c): grouped reciprocal across the mt pair
        const float aa0 = fminf(cs[0] * (2.0f * LOG2E), 30.0f);
        const float aa1 = fminf(cs[1] * (2.0f * LOG2E), 30.0f);
        const float Dq0 = 1.0f + __builtin_amdgcn_exp2f(aa0);
        const float Dq1 = 1.0f + __builtin_amdgcn_exp2f(aa1);
        const float rq = __builtin_amdgcn_rcpf(Dq0 * Dq1);
        const float hh0 = og[0] * fmaf(-2.0f, rq * Dq1, 1.0f);
        const float hh1 = og[1] * fmaf(-2.0f, rq * Dq0, 1.0f);

        // ---- h digit encode (magic-number) + packed writes ----
        if (sc < 63) {
            const int t0 = __float_as_int(fmaf(hh0, 8192.0f, 12582912.0f)) - 0x4B400000;
            const int t1 = __float_as_int(fmaf(hh1, 8192.0f, 12582912.0f)) - 0x4B400000;
            const int d10 = (t0 + 64) >> 7;
            const int d20 = t0 - (d10 << 7);
            const int d11 = (t1 + 64) >> 7;
            const int d21 = t1 - (d11 << 7);
            *(unsigned short*)(Hb + wa[gc]) =
                (unsigned short)__builtin_amdgcn_perm((unsigned)d11, (unsigned)d10, 0x0400);
            *(unsigned short*)(Hb + wa[gc] + 8192) =
                (unsigned short)__builtin_amdgcn_perm((unsigned)d21, (unsigned)d20, 0x0400);
        } else {
            float* o = hout + ((size_t)dir * B_TOTAL + b0 + gc * 16 + l15) * 128;
            o[hu0] = hh0;
            o[hu1] = hh1;
        }
        wa[gc] ^= 0x1000;
        __syncthreads();
    }
}

// ---------------- Kernel C: final FC ----------------
__global__ __launch_bounds__(256) void k_final(
    const float* __restrict__ hout,        // [2][B][128]
    const float* __restrict__ device_idx,  // [B]
    const float* __restrict__ fc_w,        // [257]
    const float* __restrict__ fc_b,        // [1]
    float* __restrict__ y)                 // [B]
{
    const int wave = threadIdx.x >> 6;
    const int lane = threadIdx.x & 63;
    const int b = blockIdx.x * 4 + wave;
    const float* hf = hout + (size_t)b * 128;
    const float* hb = hout + ((size_t)B_TOTAL + b) * 128;
    float p = fc_w[1 + lane]        * hf[lane]
            + fc_w[1 + 64 + lane]   * hf[64 + lane]
            + fc_w[129 + lane]      * hb[lane]
            + fc_w[129 + 64 + lane] * hb[64 + lane];
    #pragma unroll
    for (int off = 32; off; off >>= 1) p += __shfl_xor(p, off, 64);
    if (lane == 0) y[b] = p + fc_w[0] * device_idx[b] + fc_b[0];
}

extern "C" void kernel_launch(void* const* d_in, const int* in_sizes, int n_in,
                              void* d_out, int out_size, void* d_ws, size_t ws_size,
                              hipStream_t stream) {
    const float* device_idx = (const float*)d_in[0];
    const float* matrix     = (const float*)d_in[1];
    const float* features   = (const float*)d_in[2];
    const float* Wi_f = (const float*)d_in[3];
    const float* Wh_f = (const float*)d_in[4];
    const float* bi_f = (const float*)d_in[5];
    const float* bh_f = (const float*)d_in[6];
    const float* Wi_b = (const float*)d_in[7];
    const float* Wh_b = (const float*)d_in[8];
    const float* bi_b = (const float*)d_in[9];
    const float* bh_b = (const float*)d_in[10];
    const float* fc_w = (const float*)d_in[11];
    const float* fc_b = (const float*)d_in[12];
    float* out = (float*)d_out;

    float* ws = (float*)d_ws;
    float*          upd  = ws;                               // 1,572,864 floats
    signed char*    Wd1  = (signed char*)(ws + 1572864);     // 131,072 bytes
    signed char*    Wd2  = (signed char*)(ws + 1605632);     // 131,072 bytes
    unsigned short* AwU  = (unsigned short*)(ws + 1638400);  //  32,768 ushorts
    float*          Bq   = ws + 1654784;                     //   1,024 floats
    float*          hout = ws + 1655808;                     // 1,048,576 floats

    hipLaunchKernelGGL(k_neighbor_mean, dim3(B_TOTAL), dim3(256), 0, stream,
                       matrix, features, upd);
    hipLaunchKernelGGL(k_wprep5, dim3(644), dim3(256), 0, stream,
                       Wi_f, Wh_f, bi_f, bh_f, Wi_b, Wh_b, bi_b, bh_b,
                       Wd1, Wd2, AwU, Bq);
    hipLaunchKernelGGL(k_lstm11, dim3(B_TOTAL / 32, 2), dim3(1024), 0, stream,
                       upd, Wd1, Wd2, AwU, Bq, hout);
    hipLaunchKernelGGL(k_final, dim3(B_TOTAL / 4), dim3(256), 0, stream,
                       hout, device_idx, fc_w, fc_b, out);
}

// Round 11
// 167.168 us; speedup vs baseline: 1.0142x; 1.0074x over previous
//
#include <hip/hip_runtime.h>
#include <hip/hip_bf16.h>

#define B_TOTAL 4096
#define LOG2E 1.44269504088896f

typedef short short8 __attribute__((ext_vector_type(8)));
typedef float f32x4 __attribute__((ext_vector_type(4)));
typedef float f32x2 __attribute__((ext_vector_type(2)));
typedef int   i32x4 __attribute__((ext_vector_type(4)));

__device__ __forceinline__ unsigned short rne_bf16(float x) {
    unsigned int u = __float_as_uint(x);
    unsigned int r = (u + 0x7fffu + ((u >> 16) & 1u)) >> 16;
    return (unsigned short)r;
}
__device__ __forceinline__ unsigned int cvt2bf(float lo, float hi) {
    unsigned int r;
    asm("v_cvt_pk_bf16_f32 %0, %1, %2" : "=v"(r) : "v"(lo), "v"(hi));
    return r;
}
__device__ __forceinline__ f32x2 v2(float x) { f32x2 r; r[0] = x; r[1] = x; return r; }

// ---------------- Kernel A: neighbor mean ----------------
__global__ __launch_bounds__(256) void k_neighbor_mean(
    const float* __restrict__ matrix,   // [B,64,64]
    const float* __restrict__ features, // [B,64,6]
    float* __restrict__ upd)            // [B,64,6]
{
    __shared__ float adj[64][65];
    __shared__ float fx[64][6];
    const int b = blockIdx.x;
    const int tid = threadIdx.x;
    const float* mb_ = matrix + (size_t)b * 4096;
    for (int idx = tid; idx < 4096; idx += 256) adj[idx >> 6][idx & 63] = mb_[idx];
    const float* fb = features + (size_t)b * 384;
    for (int idx = tid; idx < 384; idx += 256) fx[idx / 6][idx % 6] = fb[idx];
    __syncthreads();
    if (tid < 64) {
        const int i = tid;
        float s0=0,s1=0,s2=0,s3=0,s4=0,s5=0,cnt=0;
        for (int j = 0; j < 64; j++) {
            float m = adj[i][j] > 0.0f ? 1.0f : 0.0f;
            cnt += m;
            s0 += m*fx[j][0]; s1 += m*fx[j][1]; s2 += m*fx[j][2];
            s3 += m*fx[j][3]; s4 += m*fx[j][4]; s5 += m*fx[j][5];
        }
        const float inv = 1.0f / (cnt + 1.0f);
        float* o = upd + (size_t)b * 384 + i * 6;
        o[0]=(s0+fx[i][0])*inv; o[1]=(s1+fx[i][1])*inv; o[2]=(s2+fx[i][2])*inv;
        o[3]=(s3+fx[i][3])*inv; o[4]=(s4+fx[i][4])*inv; o[5]=(s5+fx[i][5])*inv;
    }
}

// ---------------- Kernel W: weights -> i8 digit A-fragments (log2e-folded) ----------------
// Wd1/Wd2 [dir 2][mtg 32][kc 2][lane 64][e 16] i8:
//   n = mtg*16 + (lane&15), j = (n&3)*128 + (n>>2)   (n = 4*hu + gate)
//   ks = kc*64 + 16*(lane>>4) + e; hu_src = 8*(ks>>3) + 4*(ks&1) + ((ks&7)>>1)
//   a = Wh[j*128+hu_src] * 512*LOG2E (== 256*2*LOG2E, gate-uniform);
//   d1 = rint(a), d2 = rint((a-d1)*128)
// AwU [dir 2][mtg 32][lane 64][e 8] bf16 : Wi * (gate==2 ? 2L : L); nonzero only lane>>4==0 && e<6
// Bq  [dir 2][n 512] f32 : (bi+bh) * (gate==2 ? 2L : L)
__global__ __launch_bounds__(256) void k_wprep5(
    const float* __restrict__ Wi_f, const float* __restrict__ Wh_f,
    const float* __restrict__ bi_f, const float* __restrict__ bh_f,
    const float* __restrict__ Wi_b, const float* __restrict__ Wh_b,
    const float* __restrict__ bi_b, const float* __restrict__ bh_b,
    signed char* __restrict__ Wd1, signed char* __restrict__ Wd2,
    unsigned short* __restrict__ AwU, float* __restrict__ BqO)
{
    const int idx = blockIdx.x * 256 + threadIdx.x;   // 0..164863
    if (idx < 131072) {
        const int dir = idx >> 16;
        const int r = idx & 65535;
        const int mtg = r >> 11;
        const int kc  = (r >> 10) & 1;
        const int l   = (r >> 4) & 63;
        const int e   = r & 15;
        const int n = mtg * 16 + (l & 15);
        const int j = ((n & 3) << 7) + (n >> 2);
        const int ks = kc * 64 + 16 * (l >> 4) + e;   // 0..127
        const int hu = 8 * (ks >> 3) + 4 * (ks & 1) + ((ks & 7) >> 1);
        const float w = (dir ? Wh_b : Wh_f)[j * 128 + hu];
        const float a = w * (512.0f * LOG2E);
        const float r1 = rintf(a);
        Wd1[idx] = (signed char)(int)r1;
        Wd2[idx] = (signed char)(int)rintf((a - r1) * 128.0f);
    } else if (idx < 163840) {
        const int i2 = idx - 131072;       // 0..32767
        const int dir = i2 >> 14;
        const int r = i2 & 16383;
        const int mtg = r >> 9, l = (r >> 3) & 63, e = r & 7;
        const int n = mtg * 16 + (l & 15);
        const int j = ((n & 3) << 7) + (n >> 2);
        const float sc = ((n & 3) == 2) ? 2.0f * LOG2E : LOG2E;
        float w = 0.0f;
        if ((l >> 4) == 0 && e < 6) w = (dir ? Wi_b : Wi_f)[j * 6 + e] * sc;
        AwU[i2] = rne_bf16(w);
    } else if (idx < 164864) {
        const int i2 = idx - 163840;       // 0..1023
        const int dir = i2 >> 9;
        const int n = i2 & 511;
        const int j = ((n & 3) << 7) + (n >> 2);
        const float sc = ((n & 3) == 2) ? 2.0f * LOG2E : LOG2E;
        BqO[i2] = ((dir ? bi_b : bi_f)[j] + (dir ? bh_b : bh_f)[j]) * sc;
    }
}

// ---------------- Kernel B: group-pipelined i8 MFMA bi-LSTM, wave phase-stagger ----------------
// grid (128, 2), block 1024 (16 waves), 1 block/CU.
// Wave owns mtg {2w,2w+1} (hu 8w..8w+7) x 32 batches (groups g0=b0..b0+15, g1=+16).
// Interval iv: math(gc=iv&1 from last-interval accs) and issue(gi=gc^1, step (iv+1)>>1)
// are order-independent. Waves with (wave>>2)&1 == 0 run math->issue; ==1 run
// issue->math. Each SIMD hosts 2 waves of each phase -> trans chains of one phase
// overlap MFMA issue of the other by construction.
__global__ __launch_bounds__(1024) void k_lstm12(
    const float* __restrict__ upd,          // [4096][64][6]
    const signed char* __restrict__ Wd1,    // [2][32][2][64][16]
    const signed char* __restrict__ Wd2,    // [2][32][2][64][16]
    const unsigned short* __restrict__ AwU, // [2][32][64][8]
    const float* __restrict__ Bq,           // [2][512]
    float* __restrict__ hout)               // [2][4096][128]
{
    // H: byte = g*16384 + digit*8192 + buf*4096 + row(l15)*144 + col(p(hu))
    __shared__ i32x4 HsV[2048];   // 32 KB
    // U: byte = g*16384 + t*256 + b*16  (bf16x8 {u0..u5,0,0})
    __shared__ i32x4 UsV[2048];   // 32 KB
    char* Hb = (char*)HsV;
    char* Ub = (char*)UsV;
    const int tid  = threadIdx.x;
    const int wave = tid >> 6;
    const int lane = tid & 63;
    const int dir  = blockIdx.y;
    const int b0   = blockIdx.x * 32;
    const int l15  = lane & 15;
    const int lhi  = lane >> 4;
    const int hu0  = 8 * wave + lhi, hu1 = hu0 + 4;
    const bool issueFirst = ((wave >> 2) & 1) != 0;

    // persistent: wd 32 + awu 8 + bias 8 + cs 4
    i32x4 wd1[2][2], wd2[2][2];
    short8 awu[2];
    f32x4 bias[2];
    #pragma unroll
    for (int mt = 0; mt < 2; mt++) {
        const int mtg = 2 * wave + mt;
        #pragma unroll
        for (int kc = 0; kc < 2; kc++) {
            wd1[mt][kc] = *(const i32x4*)(Wd1 + dir * 65536 + mtg * 2048 + kc * 1024 + lane * 16);
            wd2[mt][kc] = *(const i32x4*)(Wd2 + dir * 65536 + mtg * 2048 + kc * 1024 + lane * 16);
        }
        awu[mt]  = *(const short8*)(AwU + dir * 16384 + mtg * 512 + lane * 8);
        bias[mt] = *(const f32x4*)(Bq + dir * 512 + mtg * 16 + 4 * lhi);
    }

    // stage u hi-fragments: 64 steps x 32 batches
    for (int i = tid; i < 2048; i += 1024) {
        const int t = i >> 5, b = i & 31;
        const float2* p = (const float2*)(upd + (size_t)(b0 + b) * 384 + t * 6);
        const float2 a0 = p[0], a1 = p[1], a2 = p[2];
        i32x4 v;
        v[0] = (int)cvt2bf(a0.x, a0.y);
        v[1] = (int)cvt2bf(a1.x, a1.y);
        v[2] = (int)cvt2bf(a2.x, a2.y);
        v[3] = 0;
        *(i32x4*)(Ub + (b >> 4) * 16384 + t * 256 + (b & 15) * 16) = v;
    }
    // zero all h digit planes
    for (int i = tid; i < 8192; i += 1024) ((int*)Hb)[i] = 0;

    int ra[2], wa[2];
    #pragma unroll
    for (int g = 0; g < 2; g++) {
        ra[g] = g * 16384 + 4096 + l15 * 144 + lhi * 16;        // read buf1 first
        wa[g] = g * 16384 + l15 * 144 + 8 * wave + 2 * lhi;     // write buf0 first
    }
    f32x2 cs0 = v2(0.0f), cs1 = v2(0.0f);
    f32x4 Ua[2][2];
    i32x4 Aa[2][2], Ba[2][2];
    __syncthreads();

    const i32x4 zi = {0, 0, 0, 0};
    const f32x2 one2 = v2(1.0f);
    const f32x2 two2 = v2(2.0f);

    // ---- interval building blocks (order-independent within an interval) ----
    auto ISSUE = [&](int iv) {            // issue 14 MFMAs for gi = (iv&1)^1, step (iv+1)>>1
        const int gi = (iv & 1) ^ 1;
        const int si = (iv + 1) >> 1;
        const int tt = dir ? (63 - si) : si;
        const short8 fu = *(const short8*)(Ub + gi * 16384 + tt * 256 + l15 * 16);
        const i32x4 h1k0 = *(const i32x4*)(Hb + ra[gi]);
        const i32x4 h1k1 = *(const i32x4*)(Hb + ra[gi] + 64);
        const i32x4 h2k0 = *(const i32x4*)(Hb + ra[gi] + 8192);
        const i32x4 h2k1 = *(const i32x4*)(Hb + ra[gi] + 8256);
        ra[gi] ^= 0x1000;
        __builtin_amdgcn_s_setprio(1);
        #pragma unroll
        for (int mt = 0; mt < 2; mt++) {
            Ua[gi][mt] = __builtin_amdgcn_mfma_f32_16x16x32_bf16(awu[mt], fu, bias[mt], 0, 0, 0);
            i32x4 a = __builtin_amdgcn_mfma_i32_16x16x64_i8(wd1[mt][0], h1k0, zi, 0, 0, 0);
            a = __builtin_amdgcn_mfma_i32_16x16x64_i8(wd1[mt][1], h1k1, a, 0, 0, 0);
            i32x4 b = __builtin_amdgcn_mfma_i32_16x16x64_i8(wd1[mt][0], h2k0, zi, 0, 0, 0);
            b = __builtin_amdgcn_mfma_i32_16x16x64_i8(wd1[mt][1], h2k1, b, 0, 0, 0);
            b = __builtin_amdgcn_mfma_i32_16x16x64_i8(wd2[mt][0], h1k0, b, 0, 0, 0);
            b = __builtin_amdgcn_mfma_i32_16x16x64_i8(wd2[mt][1], h1k1, b, 0, 0, 0);
            Aa[gi][mt] = a; Ba[gi][mt] = b;
        }
        __builtin_amdgcn_s_setprio(0);
    };

    auto MATH = [&](int gc, int sc) {     // full cell math for gc from last-interval accs
        f32x2& cs = gc ? cs1 : cs0;
        f32x2 ex[4];
        #pragma unroll
        for (int g = 0; g < 4; g++) {
            const int T0 = (Aa[gc][0][g] << 7) + Ba[gc][0][g];
            const int T1 = (Aa[gc][1][g] << 7) + Ba[gc][1][g];
            float a0, a1;
            if (g == 2) {
                a0 = fmaf((float)T0,  0x1p-21f,  Ua[gc][0][g]);
                a1 = fmaf((float)T1,  0x1p-21f,  Ua[gc][1][g]);
            } else {
                a0 = fmaf((float)T0, -0x1p-22f, -Ua[gc][0][g]);
                a1 = fmaf((float)T1, -0x1p-22f, -Ua[gc][1][g]);
            }
            ex[g][0] = __builtin_amdgcn_exp2f(a0);
            ex[g][1] = __builtin_amdgcn_exp2f(a1);
        }
        const f32x2 D0 = ex[0] + one2;
        const f32x2 D1 = ex[1] + one2;
        const f32x2 D2 = ex[2] + one2;
        const f32x2 D3 = ex[3] + one2;
        const f32x2 P2 = D0 * D1, P3 = P2 * D2, P4 = P3 * D3;
        const float rall = __builtin_amdgcn_rcpf(P4[0] * P4[1]);
        f32x2 rv;
        rv[0] = rall * P4[1];
        rv[1] = rall * P4[0];
        const f32x2 Q2 = D3 * D2, Q3 = Q2 * D1;
        const f32x2 ig = rv * Q3;
        const f32x2 fg = rv * Q2 * D0;
        const f32x2 og = rv * P3;
        const f32x2 gg = one2 - two2 * (rv * P2 * D3);
        cs = fg * cs + ig * gg;
        const float aa0 = fminf(cs[0] * (2.0f * LOG2E), 30.0f);
        const float aa1 = fminf(cs[1] * (2.0f * LOG2E), 30.0f);
        const float Dq0 = 1.0f + __builtin_amdgcn_exp2f(aa0);
        const float Dq1 = 1.0f + __builtin_amdgcn_exp2f(aa1);
        const float rq = __builtin_amdgcn_rcpf(Dq0 * Dq1);
        const float hh0 = og[0] * fmaf(-2.0f, rq * Dq1, 1.0f);
        const float hh1 = og[1] * fmaf(-2.0f, rq * Dq0, 1.0f);

        if (sc < 63) {
            const int t0 = __float_as_int(fmaf(hh0, 8192.0f, 12582912.0f)) - 0x4B400000;
            const int t1 = __float_as_int(fmaf(hh1, 8192.0f, 12582912.0f)) - 0x4B400000;
            const int d10 = (t0 + 64) >> 7;
            const int d20 = t0 - (d10 << 7);
            const int d11 = (t1 + 64) >> 7;
            const int d21 = t1 - (d11 << 7);
            *(unsigned short*)(Hb + wa[gc]) =
                (unsigned short)__builtin_amdgcn_perm((unsigned)d11, (unsigned)d10, 0x0400);
            *(unsigned short*)(Hb + wa[gc] + 8192) =
                (unsigned short)__builtin_amdgcn_perm((unsigned)d21, (unsigned)d20, 0x0400);
        } else {
            float* o = hout + ((size_t)dir * B_TOTAL + b0 + gc * 16 + l15) * 128;
            o[hu0] = hh0;
            o[hu1] = hh1;
        }
        wa[gc] ^= 0x1000;
    };

    // prologue: issue group 0, step 0 (h = zeros)
    {
        const int tt = dir ? 63 : 0;
        const short8 fu = *(const short8*)(Ub + tt * 256 + l15 * 16);
        const i32x4 h1k0 = *(const i32x4*)(Hb + ra[0]);
        const i32x4 h1k1 = *(const i32x4*)(Hb + ra[0] + 64);
        const i32x4 h2k0 = *(const i32x4*)(Hb + ra[0] + 8192);
        const i32x4 h2k1 = *(const i32x4*)(Hb + ra[0] + 8256);
        ra[0] ^= 0x1000;
        #pragma unroll
        for (int mt = 0; mt < 2; mt++) {
            Ua[0][mt] = __builtin_amdgcn_mfma_f32_16x16x32_bf16(awu[mt], fu, bias[mt], 0, 0, 0);
            i32x4 a = __builtin_amdgcn_mfma_i32_16x16x64_i8(wd1[mt][0], h1k0, zi, 0, 0, 0);
            a = __builtin_amdgcn_mfma_i32_16x16x64_i8(wd1[mt][1], h1k1, a, 0, 0, 0);
            i32x4 b = __builtin_amdgcn_mfma_i32_16x16x64_i8(wd1[mt][0], h2k0, zi, 0, 0, 0);
            b = __builtin_amdgcn_mfma_i32_16x16x64_i8(wd1[mt][1], h2k1, b, 0, 0, 0);
            b = __builtin_amdgcn_mfma_i32_16x16x64_i8(wd2[mt][0], h1k0, b, 0, 0, 0);
            b = __builtin_amdgcn_mfma_i32_16x16x64_i8(wd2[mt][1], h1k1, b, 0, 0, 0);
            Aa[0][mt] = a; Ba[0][mt] = b;
        }
    }

    #pragma unroll 2
    for (int iv = 0; iv < 128; ++iv) {
        const int gc = iv & 1;
        const int sc = iv >> 1;
        if (issueFirst) {
            if (iv < 127) ISSUE(iv);
            MATH(gc, sc);
        } else {
            MATH(gc, sc);
            if (iv < 127) ISSUE(iv);
        }
        __syncthreads();
    }
}

// ---------------- Kernel C: final FC ----------------
__global__ __launch_bounds__(256) void k_final(
    const float* __restrict__ hout,        // [2][B][128]
    const float* __restrict__ device_idx,  // [B]
    const float* __restrict__ fc_w,        // [257]
    const float* __restrict__ fc_b,        // [1]
    float* __restrict__ y)                 // [B]
{
    const int wave = threadIdx.x >> 6;
    const int lane = threadIdx.x & 63;
    const int b = blockIdx.x * 4 + wave;
    const float* hf = hout + (size_t)b * 128;
    const float* hb = hout + ((size_t)B_TOTAL + b) * 128;
    float p = fc_w[1 + lane]        * hf[lane]
            + fc_w[1 + 64 + lane]   * hf[64 + lane]
            + fc_w[129 + lane]      * hb[lane]
            + fc_w[129 + 64 + lane] * hb[64 + lane];
    #pragma unroll
    for (int off = 32; off; off >>= 1) p += __shfl_xor(p, off, 64);
    if (lane == 0) y[b] = p + fc_w[0] * device_idx[b] + fc_b[0];
}

extern "C" void kernel_launch(void* const* d_in, const int* in_sizes, int n_in,
                              void* d_out, int out_size, void* d_ws, size_t ws_size,
                              hipStream_t stream) {
    const float* device_idx = (const float*)d_in[0];
    const float* matrix     = (const float*)d_in[1];
    const float* features   = (const float*)d_in[2];
    const float* Wi_f = (const float*)d_in[3];
    const float* Wh_f = (const float*)d_in[4];
    const float* bi_f = (const float*)d_in[5];
    const float* bh_f = (const float*)d_in[6];
    const float* Wi_b = (const float*)d_in[7];
    const float* Wh_b = (const float*)d_in[8];
    const float* bi_b = (const float*)d_in[9];
    const float* bh_b = (const float*)d_in[10];
    const float* fc_w = (const float*)d_in[11];
    const float* fc_b = (const float*)d_in[12];
    float* out = (float*)d_out;

    float* ws = (float*)d_ws;
    float*          upd  = ws;                               // 1,572,864 floats
    signed char*    Wd1  = (signed char*)(ws + 1572864);     // 131,072 bytes
    signed char*    Wd2  = (signed char*)(ws + 1605632);     // 131,072 bytes
    unsigned short* AwU  = (unsigned short*)(ws + 1638400);  //  32,768 ushorts
    float*          Bq   = ws + 1654784;                     //   1,024 floats
    float*          hout = ws + 1655808;                     // 1,048,576 floats

    hipLaunchKernelGGL(k_neighbor_mean, dim3(B_TOTAL), dim3(256), 0, stream,
                       matrix, features, upd);
    hipLaunchKernelGGL(k_wprep5, dim3(644), dim3(256), 0, stream,
                       Wi_f, Wh_f, bi_f, bh_f, Wi_b, Wh_b, bi_b, bh_b,
                       Wd1, Wd2, AwU, Bq);
    hipLaunchKernelGGL(k_lstm12, dim3(B_TOTAL / 32, 2), dim3(1024), 0, stream,
                       upd, Wd1, Wd2, AwU, Bq, hout);
    hipLaunchKernelGGL(k_final, dim3(B_TOTAL / 4), dim3(256), 0, stream,
                       hout, device_idx, fc_w, fc_b, out);
}

// Round 12
// 161.070 us; speedup vs baseline: 1.0526x; 1.0379x over previous
//
#include <hip/hip_runtime.h>
#include <hip/hip_bf16.h>

#define B_TOTAL 4096
#define LOG2E 1.44269504088896f

typedef short short8 __attribute__((ext_vector_type(8)));
typedef float f32x4 __attribute__((ext_vector_type(4)));
typedef float f32x2 __attribute__((ext_vector_type(2)));
typedef int   i32x4 __attribute__((ext_vector_type(4)));

__device__ __forceinline__ unsigned short rne_bf16(float x) {
    unsigned int u = __float_as_uint(x);
    unsigned int r = (u + 0x7fffu + ((u >> 16) & 1u)) >> 16;
    return (unsigned short)r;
}
__device__ __forceinline__ unsigned int cvt2bf(float lo, float hi) {
    unsigned int r;
    asm("v_cvt_pk_bf16_f32 %0, %1, %2" : "=v"(r) : "v"(lo), "v"(hi));
    return r;
}
__device__ __forceinline__ f32x2 v2(float x) { f32x2 r; r[0] = x; r[1] = x; return r; }

// ---------------- Kernel A: neighbor mean ----------------
__global__ __launch_bounds__(256) void k_neighbor_mean(
    const float* __restrict__ matrix,   // [B,64,64]
    const float* __restrict__ features, // [B,64,6]
    float* __restrict__ upd)            // [B,64,6]
{
    __shared__ float adj[64][65];
    __shared__ float fx[64][6];
    const int b = blockIdx.x;
    const int tid = threadIdx.x;
    const float* mb_ = matrix + (size_t)b * 4096;
    for (int idx = tid; idx < 4096; idx += 256) adj[idx >> 6][idx & 63] = mb_[idx];
    const float* fb = features + (size_t)b * 384;
    for (int idx = tid; idx < 384; idx += 256) fx[idx / 6][idx % 6] = fb[idx];
    __syncthreads();
    if (tid < 64) {
        const int i = tid;
        float s0=0,s1=0,s2=0,s3=0,s4=0,s5=0,cnt=0;
        for (int j = 0; j < 64; j++) {
            float m = adj[i][j] > 0.0f ? 1.0f : 0.0f;
            cnt += m;
            s0 += m*fx[j][0]; s1 += m*fx[j][1]; s2 += m*fx[j][2];
            s3 += m*fx[j][3]; s4 += m*fx[j][4]; s5 += m*fx[j][5];
        }
        const float inv = 1.0f / (cnt + 1.0f);
        float* o = upd + (size_t)b * 384 + i * 6;
        o[0]=(s0+fx[i][0])*inv; o[1]=(s1+fx[i][1])*inv; o[2]=(s2+fx[i][2])*inv;
        o[3]=(s3+fx[i][3])*inv; o[4]=(s4+fx[i][4])*inv; o[5]=(s5+fx[i][5])*inv;
    }
}

// ---------------- Kernel W: weights -> i8 digit A-fragments (log2e-folded) ----------------
// Wd1/Wd2 [dir 2][mtg 32][kc 2][lane 64][e 16] i8:
//   n = mtg*16 + (lane&15), j = (n&3)*128 + (n>>2)   (n = 4*hu + gate)
//   ks = kc*64 + 16*(lane>>4) + e; hu_src = 8*(ks>>3) + 4*(ks&1) + ((ks&7)>>1)
//   a = Wh[j*128+hu_src] * 512*LOG2E (== 256*2*LOG2E, gate-uniform);
//   d1 = rint(a), d2 = rint((a-d1)*128)
// AwU [dir 2][mtg 32][lane 64][e 8] bf16 : Wi * (gate==2 ? 2L : L); nonzero only lane>>4==0 && e<6
// Bq  [dir 2][n 512] f32 : (bi+bh) * (gate==2 ? 2L : L)
__global__ __launch_bounds__(256) void k_wprep5(
    const float* __restrict__ Wi_f, const float* __restrict__ Wh_f,
    const float* __restrict__ bi_f, const float* __restrict__ bh_f,
    const float* __restrict__ Wi_b, const float* __restrict__ Wh_b,
    const float* __restrict__ bi_b, const float* __restrict__ bh_b,
    signed char* __restrict__ Wd1, signed char* __restrict__ Wd2,
    unsigned short* __restrict__ AwU, float* __restrict__ BqO)
{
    const int idx = blockIdx.x * 256 + threadIdx.x;   // 0..164863
    if (idx < 131072) {
        const int dir = idx >> 16;
        const int r = idx & 65535;
        const int mtg = r >> 11;
        const int kc  = (r >> 10) & 1;
        const int l   = (r >> 4) & 63;
        const int e   = r & 15;
        const int n = mtg * 16 + (l & 15);
        const int j = ((n & 3) << 7) + (n >> 2);
        const int ks = kc * 64 + 16 * (l >> 4) + e;   // 0..127
        const int hu = 8 * (ks >> 3) + 4 * (ks & 1) + ((ks & 7) >> 1);
        const float w = (dir ? Wh_b : Wh_f)[j * 128 + hu];
        const float a = w * (512.0f * LOG2E);
        const float r1 = rintf(a);
        Wd1[idx] = (signed char)(int)r1;
        Wd2[idx] = (signed char)(int)rintf((a - r1) * 128.0f);
    } else if (idx < 163840) {
        const int i2 = idx - 131072;       // 0..32767
        const int dir = i2 >> 14;
        const int r = i2 & 16383;
        const int mtg = r >> 9, l = (r >> 3) & 63, e = r & 7;
        const int n = mtg * 16 + (l & 15);
        const int j = ((n & 3) << 7) + (n >> 2);
        const float sc = ((n & 3) == 2) ? 2.0f * LOG2E : LOG2E;
        float w = 0.0f;
        if ((l >> 4) == 0 && e < 6) w = (dir ? Wi_b : Wi_f)[j * 6 + e] * sc;
        AwU[i2] = rne_bf16(w);
    } else if (idx < 164864) {
        const int i2 = idx - 163840;       // 0..1023
        const int dir = i2 >> 9;
        const int n = i2 & 511;
        const int j = ((n & 3) << 7) + (n >> 2);
        const float sc = ((n & 3) == 2) ? 2.0f * LOG2E : LOG2E;
        BqO[i2] = ((dir ? bi_b : bi_f)[j] + (dir ? bh_b : bh_f)[j]) * sc;
    }
}

// ---------------- Kernel B: group-pipelined i8 MFMA bi-LSTM, diet cell math ----------------
// grid (128, 2), block 1024 (16 waves), 1 block/CU.
// Wave owns mtg {2w,2w+1} (hu 8w..8w+7) x 32 batches (groups g0=b0..b0+15, g1=+16).
// Interval iv: [cell math for gc=iv&1 from accs issued last interval] ->
//              [issue 14 MFMAs for gi=gc^1, step (iv+1)>>1] -> barrier.
// Main loop iv=0..125 branch-free; intervals 126/127 peeled (hout epilogue).
__global__ __launch_bounds__(1024) void k_lstm13(
    const float* __restrict__ upd,          // [4096][64][6]
    const signed char* __restrict__ Wd1,    // [2][32][2][64][16]
    const signed char* __restrict__ Wd2,    // [2][32][2][64][16]
    const unsigned short* __restrict__ AwU, // [2][32][64][8]
    const float* __restrict__ Bq,           // [2][512]
    float* __restrict__ hout)               // [2][4096][128]
{
    // H: byte = g*16384 + digit*8192 + buf*4096 + row(l15)*144 + col(p(hu))
    __shared__ i32x4 HsV[2048];   // 32 KB
    // U: byte = g*16384 + t*256 + b*16  (bf16x8 {u0..u5,0,0})
    __shared__ i32x4 UsV[2048];   // 32 KB
    char* Hb = (char*)HsV;
    char* Ub = (char*)UsV;
    const int tid  = threadIdx.x;
    const int wave = tid >> 6;
    const int lane = tid & 63;
    const int dir  = blockIdx.y;
    const int b0   = blockIdx.x * 32;
    const int l15  = lane & 15;
    const int lhi  = lane >> 4;
    const int hu0  = 8 * wave + lhi, hu1 = hu0 + 4;

    // persistent: wd 32 + awu 8 + bias 8 + cs 4
    i32x4 wd1[2][2], wd2[2][2];
    short8 awu[2];
    f32x4 bias[2];
    #pragma unroll
    for (int mt = 0; mt < 2; mt++) {
        const int mtg = 2 * wave + mt;
        #pragma unroll
        for (int kc = 0; kc < 2; kc++) {
            wd1[mt][kc] = *(const i32x4*)(Wd1 + dir * 65536 + mtg * 2048 + kc * 1024 + lane * 16);
            wd2[mt][kc] = *(const i32x4*)(Wd2 + dir * 65536 + mtg * 2048 + kc * 1024 + lane * 16);
        }
        awu[mt]  = *(const short8*)(AwU + dir * 16384 + mtg * 512 + lane * 8);
        bias[mt] = *(const f32x4*)(Bq + dir * 512 + mtg * 16 + 4 * lhi);
    }

    // stage u hi-fragments: 64 steps x 32 batches
    for (int i = tid; i < 2048; i += 1024) {
        const int t = i >> 5, b = i & 31;
        const float2* p = (const float2*)(upd + (size_t)(b0 + b) * 384 + t * 6);
        const float2 a0 = p[0], a1 = p[1], a2 = p[2];
        i32x4 v;
        v[0] = (int)cvt2bf(a0.x, a0.y);
        v[1] = (int)cvt2bf(a1.x, a1.y);
        v[2] = (int)cvt2bf(a2.x, a2.y);
        v[3] = 0;
        *(i32x4*)(Ub + (b >> 4) * 16384 + t * 256 + (b & 15) * 16) = v;
    }
    // zero all h digit planes
    for (int i = tid; i < 8192; i += 1024) ((int*)Hb)[i] = 0;

    // addresses: h read/write (buf toggle XOR 0x1000), u pointers advance +/-256 per step
    int ra[2], wa[2], ua[2];
    const int ustride = dir ? -256 : 256;
    #pragma unroll
    for (int g = 0; g < 2; g++) {
        ra[g] = g * 16384 + 4096 + l15 * 144 + lhi * 16;        // read buf1 first
        wa[g] = g * 16384 + l15 * 144 + 8 * wave + 2 * lhi;     // write buf0 first
        ua[g] = g * 16384 + (dir ? 63 * 256 : 0) + l15 * 16;    // step 0 of this dir
    }
    f32x2 cs0 = v2(0.0f), cs1 = v2(0.0f);
    f32x4 Ua[2][2];
    i32x4 Aa[2][2], Ba[2][2];
    __syncthreads();

    const i32x4 zi = {0, 0, 0, 0};
    const f32x2 one2 = v2(1.0f);

    // ---- issue 14 MFMAs for group g (u from ua[g], h from ra[g]; both then advance) ----
    auto ISSUE = [&](int g) {
        const short8 fu = *(const short8*)(Ub + ua[g]);
        ua[g] += ustride;
        const i32x4 h1k0 = *(const i32x4*)(Hb + ra[g]);
        const i32x4 h1k1 = *(const i32x4*)(Hb + ra[g] + 64);
        const i32x4 h2k0 = *(const i32x4*)(Hb + ra[g] + 8192);
        const i32x4 h2k1 = *(const i32x4*)(Hb + ra[g] + 8256);
        ra[g] ^= 0x1000;
        #pragma unroll
        for (int mt = 0; mt < 2; mt++) {
            Ua[g][mt] = __builtin_amdgcn_mfma_f32_16x16x32_bf16(awu[mt], fu, bias[mt], 0, 0, 0);
            i32x4 a = __builtin_amdgcn_mfma_i32_16x16x64_i8(wd1[mt][0], h1k0, zi, 0, 0, 0);
            a = __builtin_amdgcn_mfma_i32_16x16x64_i8(wd1[mt][1], h1k1, a, 0, 0, 0);
            i32x4 b = __builtin_amdgcn_mfma_i32_16x16x64_i8(wd1[mt][0], h2k0, zi, 0, 0, 0);
            b = __builtin_amdgcn_mfma_i32_16x16x64_i8(wd1[mt][1], h2k1, b, 0, 0, 0);
            b = __builtin_amdgcn_mfma_i32_16x16x64_i8(wd2[mt][0], h1k0, b, 0, 0, 0);
            b = __builtin_amdgcn_mfma_i32_16x16x64_i8(wd2[mt][1], h1k1, b, 0, 0, 0);
            Aa[g][mt] = a; Ba[g][mt] = b;
        }
    };

    // ---- gates + cell update for group gc; returns h pair (hh0, hh1) ----
    auto CELL = [&](int gc, float& hh0, float& hh1) {
        f32x2& cs = gc ? cs1 : cs0;
        f32x2 ex[4];
        #pragma unroll
        for (int g = 0; g < 4; g++) {
            const int T0 = (Aa[gc][0][g] << 7) + Ba[gc][0][g];
            const int T1 = (Aa[gc][1][g] << 7) + Ba[gc][1][g];
            float a0, a1;
            if (g == 2) {
                a0 = fmaf((float)T0,  0x1p-21f,  Ua[gc][0][g]);
                a1 = fmaf((float)T1,  0x1p-21f,  Ua[gc][1][g]);
            } else {
                a0 = fmaf((float)T0, -0x1p-22f, -Ua[gc][0][g]);
                a1 = fmaf((float)T1, -0x1p-22f, -Ua[gc][1][g]);
            }
            ex[g][0] = __builtin_amdgcn_exp2f(a0);
            ex[g][1] = __builtin_amdgcn_exp2f(a1);
        }
        // common-denominator cell update:
        // c' = (c*D0*D2 + D1*(D2-2)) / (D0*D1*D2);  o = 1/D3
        const f32x2 D0 = ex[0] + one2;
        const f32x2 D1 = ex[1] + one2;
        const f32x2 D2 = ex[2] + one2;
        const f32x2 D3 = ex[3] + one2;
        const f32x2 M  = D0 * D2;
        const f32x2 M3 = M * D1;
        const f32x2 M4 = M3 * D3;
        f32x2 r;
        r[0] = __builtin_amdgcn_rcpf(M4[0]);
        r[1] = __builtin_amdgcn_rcpf(M4[1]);
        const f32x2 rD3 = r * D3;            // 1/(D0 D1 D2)
        const f32x2 og  = r * M3;            // 1/D3
        const f32x2 t2  = (ex[2] - one2) * D1;   // D1*(D2-2)
        cs = (cs * M + t2) * rD3;
        // tanh(c'): grouped reciprocal across the mt pair (clamp keeps Dq finite)
        const float aa0 = fminf(cs[0] * (2.0f * LOG2E), 30.0f);
        const float aa1 = fminf(cs[1] * (2.0f * LOG2E), 30.0f);
        const float Dq0 = 1.0f + __builtin_amdgcn_exp2f(aa0);
        const float Dq1 = 1.0f + __builtin_amdgcn_exp2f(aa1);
        const float rq = __builtin_amdgcn_rcpf(Dq0 * Dq1);
        hh0 = og[0] * fmaf(-2.0f, rq * Dq1, 1.0f);
        hh1 = og[1] * fmaf(-2.0f, rq * Dq0, 1.0f);
    };

    auto STORE_DIGITS = [&](int gc, float hh0, float hh1) {
        const int t0 = __float_as_int(fmaf(hh0, 8192.0f, 12582912.0f)) - 0x4B400000;
        const int t1 = __float_as_int(fmaf(hh1, 8192.0f, 12582912.0f)) - 0x4B400000;
        const int d10 = (t0 + 64) >> 7;
        const int d20 = t0 - (d10 << 7);
        const int d11 = (t1 + 64) >> 7;
        const int d21 = t1 - (d11 << 7);
        *(unsigned short*)(Hb + wa[gc]) =
            (unsigned short)__builtin_amdgcn_perm((unsigned)d11, (unsigned)d10, 0x0400);
        *(unsigned short*)(Hb + wa[gc] + 8192) =
            (unsigned short)__builtin_amdgcn_perm((unsigned)d21, (unsigned)d20, 0x0400);
        wa[gc] ^= 0x1000;
    };

    // prologue: issue group 0, step 0 (h = zeros)
    ISSUE(0);

    // main loop: intervals 0..125, branch-free (sc <= 62)
    #pragma unroll 2
    for (int iv = 0; iv < 126; ++iv) {
        const int gc = iv & 1;
        float hh0, hh1;
        CELL(gc, hh0, hh1);
        ISSUE(gc ^ 1);
        STORE_DIGITS(gc, hh0, hh1);
        __syncthreads();
    }
    // interval 126: gc=0, step 63 -> hout; still issue g1's step-63 MFMAs
    {
        float hh0, hh1;
        CELL(0, hh0, hh1);
        ISSUE(1);
        float* o = hout + ((size_t)dir * B_TOTAL + b0 + l15) * 128;
        o[hu0] = hh0;
        o[hu1] = hh1;
        __syncthreads();
    }
    // interval 127: gc=1, step 63 -> hout
    {
        float hh0, hh1;
        CELL(1, hh0, hh1);
        float* o = hout + ((size_t)dir * B_TOTAL + b0 + 16 + l15) * 128;
        o[hu0] = hh0;
        o[hu1] = hh1;
    }
}

// ---------------- Kernel C: final FC ----------------
__global__ __launch_bounds__(256) void k_final(
    const float* __restrict__ hout,        // [2][B][128]
    const float* __restrict__ device_idx,  // [B]
    const float* __restrict__ fc_w,        // [257]
    const float* __restrict__ fc_b,        // [1]
    float* __restrict__ y)                 // [B]
{
    const int wave = threadIdx.x >> 6;
    const int lane = threadIdx.x & 63;
    const int b = blockIdx.x * 4 + wave;
    const float* hf = hout + (size_t)b * 128;
    const float* hb = hout + ((size_t)B_TOTAL + b) * 128;
    float p = fc_w[1 + lane]        * hf[lane]
            + fc_w[1 + 64 + lane]   * hf[64 + lane]
            + fc_w[129 + lane]      * hb[lane]
            + fc_w[129 + 64 + lane] * hb[64 + lane];
    #pragma unroll
    for (int off = 32; off; off >>= 1) p += __shfl_xor(p, off, 64);
    if (lane == 0) y[b] = p + fc_w[0] * device_idx[b] + fc_b[0];
}

extern "C" void kernel_launch(void* const* d_in, const int* in_sizes, int n_in,
                              void* d_out, int out_size, void* d_ws, size_t ws_size,
                              hipStream_t stream) {
    const float* device_idx = (const float*)d_in[0];
    const float* matrix     = (const float*)d_in[1];
    const float* features   = (const float*)d_in[2];
    const float* Wi_f = (const float*)d_in[3];
    const float* Wh_f = (const float*)d_in[4];
    const float* bi_f = (const float*)d_in[5];
    const float* bh_f = (const float*)d_in[6];
    const float* Wi_b = (const float*)d_in[7];
    const float* Wh_b = (const float*)d_in[8];
    const float* bi_b = (const float*)d_in[9];
    const float* bh_b = (const float*)d_in[10];
    const float* fc_w = (const float*)d_in[11];
    const float* fc_b = (const float*)d_in[12];
    float* out = (float*)d_out;

    float* ws = (float*)d_ws;
    float*          upd  = ws;                               // 1,572,864 floats
    signed char*    Wd1  = (signed char*)(ws + 1572864);     // 131,072 bytes
    signed char*    Wd2  = (signed char*)(ws + 1605632);     // 131,072 bytes
    unsigned short* AwU  = (unsigned short*)(ws + 1638400);  //  32,768 ushorts
    float*          Bq   = ws + 1654784;                     //   1,024 floats
    float*          hout = ws + 1655808;                     // 1,048,576 floats

    hipLaunchKernelGGL(k_neighbor_mean, dim3(B_TOTAL), dim3(256), 0, stream,
                       matrix, features, upd);
    hipLaunchKernelGGL(k_wprep5, dim3(644), dim3(256), 0, stream,
                       Wi_f, Wh_f, bi_f, bh_f, Wi_b, Wh_b, bi_b, bh_b,
                       Wd1, Wd2, AwU, Bq);
    hipLaunchKernelGGL(k_lstm13, dim3(B_TOTAL / 32, 2), dim3(1024), 0, stream,
                       upd, Wd1, Wd2, AwU, Bq, hout);
    hipLaunchKernelGGL(k_final, dim3(B_TOTAL / 4), dim3(256), 0, stream,
                       hout, device_idx, fc_w, fc_b, out);
}